// Round 4
// baseline (134.646 us; speedup 1.0000x reference)
//
#include <hip/hip_runtime.h>

// Fisher-Kolmogorov PDE: out = div(D * grad(u)) + rho * u * (1 - u)
// grad = central difference with replicate (edge) padding, applied twice.
// Shape: [B=4, C=1, D=192, H=192, W=192], float32.
//
// R1 structure (one block per contiguous x-row, one thread per voxel) plus an
// XCD-aware bijective block swizzle: physical blocks on XCD k (k = bid%8 under
// round-robin dispatch) are remapped to one contiguous chunk of 18432 rows
// (96 consecutive z-planes), so the y+-2 / z+-2 stencil reuse stays inside a
// single XCD's 4 MB L2 instead of being duplicated across all 8 L2s via L3.

#define NX 192
#define NROWS (4 * NX * NX)        // 147456 rows (b,z,y)
#define NXCD 8
#define CHUNK (NROWS / NXCD)       // 18432 rows per XCD

__global__ __launch_bounds__(192)
void fk_kernel(const float* __restrict__ u,
               const float* __restrict__ Dd,
               const float* __restrict__ rho,
               float* __restrict__ out)
{
    const int x = threadIdx.x;                   // 0..191 along W (contiguous)

    // XCD-aware bijective swizzle (NROWS % 8 == 0): XCD k gets rows
    // [k*CHUNK, (k+1)*CHUNK), traversed y-fastest then z.
    const int bid = blockIdx.x;
    int row = (bid & (NXCD - 1)) * CHUNK + (bid >> 3);

    const int y = row % NX;
    row /= NX;
    const int z = row % NX;
    const int b = row / NX;

    const int base = ((b * NX + z) * NX + y) * NX + x;

    const float uc = u[base];

    auto divterm = [&](int c, int stride) -> float {
        const int n = NX;
        const int jp  = (c + 1 < n) ? (c + 1) : (n - 1);
        const int jm  = (c - 1 > 0) ? (c - 1) : 0;
        const int jpp = (jp + 1 < n) ? (jp + 1) : (n - 1);
        const int jpm = jp - 1;                  // >= 0 always
        const int jmp = jm + 1;                  // <= n-1 always
        const int jmm = (jm - 1 > 0) ? (jm - 1) : 0;

        const float fp = Dd[base + (jp - c) * stride] *
                         (u[base + (jpp - c) * stride] - u[base + (jpm - c) * stride]);
        const float fm = Dd[base + (jm - c) * stride] *
                         (u[base + (jmp - c) * stride] - u[base + (jmm - c) * stride]);
        return (fp - fm) * 0.25f;
    };

    const float dx = divterm(x, 1);
    const float dy = divterm(y, NX);
    const float dz = divterm(z, NX * NX);

    const float reaction = rho[base] * uc * (1.0f - uc);

    out[base] = dx + dy + dz + reaction;
}

extern "C" void kernel_launch(void* const* d_in, const int* in_sizes, int n_in,
                              void* d_out, int out_size, void* d_ws, size_t ws_size,
                              hipStream_t stream) {
    const float* u   = (const float*)d_in[0];
    const float* Dd  = (const float*)d_in[1];
    const float* rho = (const float*)d_in[2];
    float* out = (float*)d_out;

    fk_kernel<<<NROWS, NX, 0, stream>>>(u, Dd, rho, out);
}

// Round 5
// 110.794 us; speedup vs baseline: 1.2153x; 1.2153x over previous
//
#include <hip/hip_runtime.h>

// Fisher-Kolmogorov PDE: out = div(D * grad(u)) + rho * u * (1 - u)
// Reference semantics per axis (replicate padding applied to u, then to flux):
//   div[c] = 0.25 * (f(min(c+1,n-1)) - f(max(c-1,0))),
//   f(j)   = D[j] * (u[min(j+1,n-1)] - u[max(j-1,0)])      (0.5*0.5 folded)
// Shape: [B=4, C=1, 192^3], float32.
//
// LDS-staged z-march: block (32,16) computes a 64x16 (x,y) tile over 24 z-planes.
// LDS rings: u planes z-2..z+2 (5 slabs), D planes z-1..z+1 (3 slabs), slab =
// [20][68] floats with halo 2 filled from clamped (replicated) global coords.
// Per step: all 18 stencil taps from LDS (14 ds_read_b64/thread, 2 voxels);
// global path = u[z+3] + D[z+2] staging (2.66 ld/thread each), rho, out.
// Replicated halo is exact except the outermost cell per axis -> fixups.

#define NX   192
#define SP   (NX * NX)
#define TX   64
#define TY   16
#define ZC   24
#define LROW 68
#define SLAB (20 * LROW)          // 1360 floats

#define LD2(p, o) (*(const float2*)((p) + (o)))

__global__ __launch_bounds__(512, 4)
void fk_kernel(const float* __restrict__ u,
               const float* __restrict__ Dd,
               const float* __restrict__ rho,
               float* __restrict__ out)
{
    __shared__ float Ush[5 * SLAB];
    __shared__ float Dsh[3 * SLAB];

    const int tx  = threadIdx.x;           // 0..31
    const int ty  = threadIdx.y;           // 0..15
    const int tid = ty * 32 + tx;          // 0..511

    int bid = blockIdx.x;
    const int xt = bid % 3;  bid /= 3;
    const int yt = bid % 12; bid /= 12;
    const int zc = bid % 8;  bid /= 8;
    const int b  = bid;                    // 0..3

    const int x0 = xt * TX, y0 = yt * TY, z0 = zc * ZC;

    const size_t vol = (size_t)b * NX * SP;
    const float* ub = u   + vol;
    const float* db = Dd  + vol;
    const float* rb = rho + vol;
    float*       ob = out + vol;

    // staging map: flat slab position -> clamped global (y,x) offset in plane
    int g0, g1, g2;
    {
        #pragma unroll
        for (int k = 0; k < 3; ++k) {
            const int p = tid + 512 * k;
            const int pp = (p < SLAB) ? p : 0;
            const int r = pp / LROW, c = pp % LROW;
            int gy = y0 + r - 2; gy = gy < 0 ? 0 : (gy > NX - 1 ? NX - 1 : gy);
            int gx = x0 + c - 2; gx = gx < 0 ? 0 : (gx > NX - 1 ? NX - 1 : gx);
            const int go = gy * NX + gx;
            if (k == 0) g0 = go; else if (k == 1) g1 = go; else g2 = go;
        }
    }
    const bool a2 = (tid < SLAB - 1024);   // tid < 336

    // ---- ring init: u planes clamp(z0-2..z0+2), D planes clamp(z0-1..z0+1) ----
    #pragma unroll
    for (int s = 0; s < 5; ++s) {
        int pz = z0 - 2 + s; pz = pz < 0 ? 0 : pz;
        const float* src = ub + (size_t)pz * SP;
        Ush[s * SLAB + tid]       = src[g0];
        Ush[s * SLAB + tid + 512] = src[g1];
        if (a2) Ush[s * SLAB + tid + 1024] = src[g2];
    }
    #pragma unroll
    for (int s = 0; s < 3; ++s) {
        int pz = z0 - 1 + s; pz = pz < 0 ? 0 : pz;
        const float* src = db + (size_t)pz * SP;
        Dsh[s * SLAB + tid]       = src[g0];
        Dsh[s * SLAB + tid + 512] = src[g1];
        if (a2) Dsh[s * SLAB + tid + 1024] = src[g2];
    }
    __syncthreads();

    int su0 = 0, su1 = 1, su2 = 2, su3 = 3, su4 = 4;   // planes z-2..z+2
    int sd0 = 0, sd1 = 1, sd2 = 2;                     // planes z-1..z+1

    const int x  = x0 + 2 * tx;            // this thread's voxels: x, x+1
    const int y  = y0 + ty;
    const int bl = (ty + 2) * LROW + (2 * tx + 2);
    const size_t gcen = (size_t)y * NX + x;

    const bool fx0 = (x == 0);
    const bool fx1 = (x + 1 == NX - 1);
    const bool fy0 = (y == 0);
    const bool fy1 = (y == NX - 1);

    for (int iz = 0; iz < ZC; ++iz) {
        const int z = z0 + iz;
        const bool pf = (iz + 1 < ZC);     // block-uniform

        // ---- issue next-plane staging loads (hide under compute) ----
        float pu0, pu1, pu2, pd0, pd1, pd2;
        if (pf) {
            const int zu = (z + 3 > NX - 1) ? NX - 1 : z + 3;
            const int zd = (z + 2 > NX - 1) ? NX - 1 : z + 2;
            const float* us = ub + (size_t)zu * SP;
            const float* ds = db + (size_t)zd * SP;
            pu0 = us[g0]; pu1 = us[g1]; if (a2) pu2 = us[g2];
            pd0 = ds[g0]; pd1 = ds[g1]; if (a2) pd2 = ds[g2];
        }
        const float2 rc = *(const float2*)(rb + (size_t)z * SP + gcen);

        // ---- taps from LDS ----
        const float* Uc = Ush + su2 * SLAB;
        const float* Dc = Dsh + sd1 * SLAB;
        const float2 uc   = LD2(Uc, bl);
        const float2 uxm  = LD2(Uc, bl - 2);
        const float2 uxp  = LD2(Uc, bl + 2);
        const float2 uym  = LD2(Uc, bl - 2 * LROW);
        const float2 uyp  = LD2(Uc, bl + 2 * LROW);
        const float2 dc   = LD2(Dc, bl);
        const float2 dxm  = LD2(Dc, bl - 2);
        const float2 dxp  = LD2(Dc, bl + 2);
        const float2 dym  = LD2(Dc, bl - LROW);
        const float2 dyp  = LD2(Dc, bl + LROW);
        const float2 uzm2 = LD2(Ush + su0 * SLAB, bl);
        const float2 uzp2 = LD2(Ush + su4 * SLAB, bl);
        const float2 dzm  = LD2(Dsh + sd0 * SLAB, bl);
        const float2 dzp  = LD2(Dsh + sd2 * SLAB, bl);

        // ---- x axis ----
        float divx_x = dc.y  * (uxp.x - uc.x) - dxm.y * (uc.x - uxm.x);
        float divx_y = dxp.x * (uxp.y - uc.y) - dc.x  * (uc.y - uxm.y);
        if (fx0) divx_x = dc.y * (uxp.x - uc.x) - dc.x * (uc.y - uc.x);
        if (fx1) divx_y = dc.y * (uc.y - uc.x)  - dc.x * (uc.y - uxm.y);

        // ---- y axis ----
        float divy_x = dyp.x * (uyp.x - uc.x) - dym.x * (uc.x - uym.x);
        float divy_y = dyp.y * (uyp.y - uc.y) - dym.y * (uc.y - uym.y);
        if (fy0) {
            const float2 uyp1 = LD2(Uc, bl + LROW);
            divy_x = dyp.x * (uyp.x - uc.x) - dym.x * (uyp1.x - uc.x);
            divy_y = dyp.y * (uyp.y - uc.y) - dym.y * (uyp1.y - uc.y);
        }
        if (fy1) {
            const float2 uym1 = LD2(Uc, bl - LROW);
            divy_x = dyp.x * (uc.x - uym1.x) - dym.x * (uc.x - uym.x);
            divy_y = dyp.y * (uc.y - uym1.y) - dym.y * (uc.y - uym.y);
        }

        // ---- z axis (z edges are block-uniform branches) ----
        float divz_x = dzp.x * (uzp2.x - uc.x) - dzm.x * (uc.x - uzm2.x);
        float divz_y = dzp.y * (uzp2.y - uc.y) - dzm.y * (uc.y - uzm2.y);
        if (z == 0) {
            const float2 uzp1 = LD2(Ush + su3 * SLAB, bl);
            divz_x = dzp.x * (uzp2.x - uc.x) - dzm.x * (uzp1.x - uc.x);
            divz_y = dzp.y * (uzp2.y - uc.y) - dzm.y * (uzp1.y - uc.y);
        }
        if (z == NX - 1) {
            const float2 uzm1 = LD2(Ush + su1 * SLAB, bl);
            divz_x = dzp.x * (uc.x - uzm1.x) - dzm.x * (uc.x - uzm2.x);
            divz_y = dzp.y * (uc.y - uzm1.y) - dzm.y * (uc.y - uzm2.y);
        }

        // ---- reaction + store ----
        float2 o;
        o.x = 0.25f * (divx_x + divy_x + divz_x) + rc.x * uc.x * (1.0f - uc.x);
        o.y = 0.25f * (divx_y + divy_y + divz_y) + rc.y * uc.y * (1.0f - uc.y);
        *(float2*)(ob + (size_t)z * SP + gcen) = o;

        __syncthreads();                   // ring reads done
        if (pf) {
            float* Uw = Ush + su0 * SLAB;  // expiring z-2 -> becomes z+3
            float* Dw = Dsh + sd0 * SLAB;  // expiring z-1 -> becomes z+2
            Uw[tid] = pu0; Uw[tid + 512] = pu1; if (a2) Uw[tid + 1024] = pu2;
            Dw[tid] = pd0; Dw[tid + 512] = pd1; if (a2) Dw[tid + 1024] = pd2;
            int t = su0; su0 = su1; su1 = su2; su2 = su3; su3 = su4; su4 = t;
            t = sd0; sd0 = sd1; sd1 = sd2; sd2 = t;
        }
        __syncthreads();                   // new planes visible
    }
}

extern "C" void kernel_launch(void* const* d_in, const int* in_sizes, int n_in,
                              void* d_out, int out_size, void* d_ws, size_t ws_size,
                              hipStream_t stream) {
    const float* u   = (const float*)d_in[0];
    const float* Dd  = (const float*)d_in[1];
    const float* rho = (const float*)d_in[2];
    float* out = (float*)d_out;

    dim3 block(32, 16, 1);                               // 512 threads
    const int grid = 3 * 12 * 8 * 4;                     // xt*yt*zc*b = 1152
    fk_kernel<<<grid, block, 0, stream>>>(u, Dd, rho, out);
}